// Round 1
// baseline (181.139 us; speedup 1.0000x reference)
//
#include <hip/hip_runtime.h>

#define NN 100000      // nodes
#define NE 1600000     // edges
#define D  64          // feature dim
#define NBK 512        // dst buckets
#define NPB 196        // nodes per bucket; 512*196 = 100352 >= NN
#define CAP 4096       // slots per bucket (mean 3125, sd 56 -> 17 sigma)
#define CHUNK 2048     // edges per bin block (256 thr) -- was 8192; 782 blocks => ~3 blocks/CU
#define NCH ((NE + CHUNK - 1) / CHUNK)        // 782 bin blocks
#define CVTB ((NN * D / 4 + 255) / 256)       // 6250 cvt blocks

// ---- workspace: cursor[NBK] ints | bins[NBK*CAP] ints | xb[NN*D] ushort ----

typedef unsigned short u16;
typedef __attribute__((ext_vector_type(8))) short bf16x8;   // 4 VGPRs
typedef __attribute__((ext_vector_type(4))) float f32x4;

__device__ __forceinline__ u16 f32_to_bf16_rn(float f) {
    unsigned u = __float_as_uint(f);
    return (u16)((u + 0x7FFF + ((u >> 16) & 1)) >> 16);   // round-nearest-even
}
__device__ __forceinline__ float bf16_to_f32(u16 h) {
    return __uint_as_float(((unsigned)h) << 16);          // exact
}

// Fused binning + fp32->bf16 convert. R0 post-mortem: bin at NCH=196 blocks
// was <1 block/CU (occupancy 6%, VALUBusy 1.6%) -> pure latency stall. Now
// CHUNK=2048 gives 782 latency-bound bin blocks, and the BW-bound cvt work
// (6250 blocks) is co-dispatched in the same grid so its HBM traffic fills
// the machine while bin blocks wait on atomics/loads.
__global__ __launch_bounds__(256) void bin_cvt_kernel(const float* __restrict__ x,
                                                      u16* __restrict__ xb,
                                                      const int* __restrict__ ei,
                                                      int* __restrict__ cursor,
                                                      int* __restrict__ bins) {
    __shared__ int lc[NBK];
    __shared__ int lbase[NBK];
    const int t = threadIdx.x;

    if (blockIdx.x >= NCH) {
        // ---- cvt part: x (fp32) -> xb (bf16), float4 -> ushort4 ----
        int i = ((blockIdx.x - NCH) * 256 + t) * 4;       // NN*D % 4 == 0
        if (i < NN * D) {
            float4 v = *(const float4*)(x + i);
            ushort4 o;
            o.x = f32_to_bf16_rn(v.x);
            o.y = f32_to_bf16_rn(v.y);
            o.z = f32_to_bf16_rn(v.z);
            o.w = f32_to_bf16_rn(v.w);
            *(ushort4*)(xb + i) = o;
        }
        return;
    }

    // ---- bin part: LDS per-bucket counts, one global atomic per
    // (block,bucket) reserves a range, packed (loc<<17)|src writes ----
    const int base = blockIdx.x * CHUNK;

    for (int i = t; i < NBK; i += 256) lc[i] = 0;
    __syncthreads();
    #pragma unroll 4
    for (int j = 0; j < CHUNK / 256; ++j) {
        int e = base + t + j * 256;
        if (e < NE) atomicAdd(&lc[(unsigned)ei[NE + e] / NPB], 1);
    }
    __syncthreads();
    for (int i = t; i < NBK; i += 256) {
        int c = lc[i];
        lbase[i] = c ? atomicAdd(&cursor[i], c) : 0;
        lc[i] = 0;                 // reuse as local offset counter
    }
    __syncthreads();
    #pragma unroll 4
    for (int j = 0; j < CHUNK / 256; ++j) {
        int e = base + t + j * 256;
        if (e < NE) {
            int src = ei[e];
            int dst = ei[NE + e];
            int b   = (unsigned)dst / NPB;
            int loc = dst - b * NPB;                  // < 196
            int o   = atomicAdd(&lc[b], 1);
            int pos = lbase[b] + o;
            if (pos < CAP)                            // 17-sigma safety clamp
                bins[b * CAP + pos] = (loc << 17) | src;   // src < 2^17
        }
    }
}

// One 1024-thread block per bucket: LDS counting-sort of packed edges by local
// node id, then REGISTER-accumulating bf16 gather per node. Writes h to d_out.
// R0: gather unroll widened 4->8 (avg degree 16) for more loads in flight.
__global__ __launch_bounds__(1024) void agg_kernel(const float* __restrict__ x,
                                                   const u16* __restrict__ xb,
                                                   const float* __restrict__ eps,
                                                   const int* __restrict__ cursor,
                                                   const int* __restrict__ bins,
                                                   float* __restrict__ out) {
    __shared__ int sorted[CAP];    // 16 KB
    __shared__ int tmp[256];
    __shared__ int off[256];       // off[r] = start of node r; off[196] == n
    __shared__ int cur[256];
    const int b    = blockIdx.x;
    const int t    = threadIdx.x;
    const int lane = t & 63;
    const int w    = t >> 6;       // 16 waves
    const int base = b * CAP;
    const int n    = min(cursor[b], CAP);
    const float e1 = 1.0f + *eps;

    // ---- counting sort by local node id ----
    if (t < 256) tmp[t] = 0;
    __syncthreads();
    for (int i = t; i < n; i += 1024)
        atomicAdd(&tmp[bins[base + i] >> 17], 1);
    __syncthreads();
    int v = (t < 256) ? tmp[t] : 0;
    for (int o = 1; o < 256; o <<= 1) {            // inclusive scan
        int u = (t < 256 && t >= o) ? tmp[t - o] : 0;
        __syncthreads();
        if (t < 256) tmp[t] += u;
        __syncthreads();
    }
    if (t < 256) { off[t] = tmp[t] - v; cur[t] = tmp[t] - v; }
    __syncthreads();
    for (int i = t; i < n; i += 1024) {
        int pk  = bins[base + i];
        int pos = atomicAdd(&cur[pk >> 17], 1);
        sorted[pos] = pk & 0x1FFFF;
    }
    __syncthreads();

    // ---- per-node register gather (bf16 rows, fp32 accumulate) ----
    #pragma unroll
    for (int j = 0; j < 13; ++j) {
        int r = w + 16 * j;                        // 16 waves x 13 >= 196
        if (r < NPB) {
            int node = b * NPB + r;
            if (node < NN) {
                float a = e1 * x[node * D + lane]; // self term fp32
                int p  = off[r];
                int pe = off[r + 1];               // counts[196..255]=0 -> valid
                for (; p + 8 <= pe; p += 8) {      // 8 loads in flight
                    int i0 = sorted[p],     i1 = sorted[p + 1];
                    int i2 = sorted[p + 2], i3 = sorted[p + 3];
                    int i4 = sorted[p + 4], i5 = sorted[p + 5];
                    int i6 = sorted[p + 6], i7 = sorted[p + 7];
                    float v0 = bf16_to_f32(xb[i0 * D + lane]);
                    float v1 = bf16_to_f32(xb[i1 * D + lane]);
                    float v2 = bf16_to_f32(xb[i2 * D + lane]);
                    float v3 = bf16_to_f32(xb[i3 * D + lane]);
                    float v4 = bf16_to_f32(xb[i4 * D + lane]);
                    float v5 = bf16_to_f32(xb[i5 * D + lane]);
                    float v6 = bf16_to_f32(xb[i6 * D + lane]);
                    float v7 = bf16_to_f32(xb[i7 * D + lane]);
                    a += ((v0 + v1) + (v2 + v3)) + ((v4 + v5) + (v6 + v7));
                }
                for (; p + 4 <= pe; p += 4) {
                    int i0 = sorted[p],     i1 = sorted[p + 1];
                    int i2 = sorted[p + 2], i3 = sorted[p + 3];
                    float v0 = bf16_to_f32(xb[i0 * D + lane]);
                    float v1 = bf16_to_f32(xb[i1 * D + lane]);
                    float v2 = bf16_to_f32(xb[i2 * D + lane]);
                    float v3 = bf16_to_f32(xb[i3 * D + lane]);
                    a += (v0 + v1) + (v2 + v3);
                }
                for (; p < pe; ++p) a += bf16_to_f32(xb[sorted[p] * D + lane]);
                out[node * D + lane] = a;          // h staged in d_out
            }
        }
    }
}

// MFMA MLP: one wave per 16-node tile. out = relu(h@W1+b1)@W2+b2 with bf16
// 16x16x32 MFMA (fp32 accum). Layer-1 C-layout (col=lane&15,row=quad*4+reg
// [m89]) re-enters layer 2 as A-layout (A[m=lane&15][k=quad*8+j] [m120]) via
// wave-private LDS tile (no barriers). In-place on d_out.
__global__ __launch_bounds__(256, 2) void mlp_mfma_kernel(
        float* __restrict__ h,
        const float* __restrict__ W1, const float* __restrict__ b1,
        const float* __restrict__ W2, const float* __restrict__ b2) {
    __shared__ u16 lds[4][16 * 72];   // per-wave tile, row stride 72 u16 (16B-aligned)
    const int lane = threadIdx.x & 63;
    const int wv   = threadIdx.x >> 6;
    const int m    = lane & 15;       // row-in-tile / col-in-output
    const int q    = lane >> 4;       // quad
    u16* tile = &lds[wv][0];

    // Weight B-frags: B[k = s*32 + q*8 + j][n = t*16 + m]; 16 frags = 64 VGPRs.
    bf16x8 wb1[4][2], wb2[4][2];
    #pragma unroll
    for (int t = 0; t < 4; ++t)
        #pragma unroll
        for (int s = 0; s < 2; ++s) {
            bf16x8 f1, f2;
            #pragma unroll
            for (int j = 0; j < 8; ++j) {
                int k = s * 32 + q * 8 + j;
                int nn = t * 16 + m;
                f1[j] = (short)f32_to_bf16_rn(W1[k * D + nn]);
                f2[j] = (short)f32_to_bf16_rn(W2[k * D + nn]);
            }
            wb1[t][s] = f1;
            wb2[t][s] = f2;
        }
    float bias1[4], bias2[4];
    #pragma unroll
    for (int t = 0; t < 4; ++t) {
        bias1[t] = b1[t * 16 + m];
        bias2[t] = b2[t * 16 + m];
    }

    const int wave = blockIdx.x * 4 + wv;
    const int nw   = gridDim.x * 4;
    for (int ti = wave; ti < NN / 16; ti += nw) {
        const int rowbase = ti * 16;

        // Layer-1 A-frags from fp32 h: A[m][k = s*32 + q*8 + j]
        bf16x8 a1f[2];
        #pragma unroll
        for (int s = 0; s < 2; ++s) {
            const float* p = h + (rowbase + m) * D + s * 32 + q * 8;
            float4 v0 = *(const float4*)p;
            float4 v1 = *(const float4*)(p + 4);
            bf16x8 f;
            f[0] = (short)f32_to_bf16_rn(v0.x);
            f[1] = (short)f32_to_bf16_rn(v0.y);
            f[2] = (short)f32_to_bf16_rn(v0.z);
            f[3] = (short)f32_to_bf16_rn(v0.w);
            f[4] = (short)f32_to_bf16_rn(v1.x);
            f[5] = (short)f32_to_bf16_rn(v1.y);
            f[6] = (short)f32_to_bf16_rn(v1.z);
            f[7] = (short)f32_to_bf16_rn(v1.w);
            a1f[s] = f;
        }

        // Layer 1: 4 n-tiles x 2 k-steps
        #pragma unroll
        for (int t = 0; t < 4; ++t) {
            f32x4 c = {0.f, 0.f, 0.f, 0.f};
            c = __builtin_amdgcn_mfma_f32_16x16x32_bf16(a1f[0], wb1[t][0], c, 0, 0, 0);
            c = __builtin_amdgcn_mfma_f32_16x16x32_bf16(a1f[1], wb1[t][1], c, 0, 0, 0);
            // bias + relu, store C-layout -> LDS bf16 tile
            #pragma unroll
            for (int r = 0; r < 4; ++r) {
                float vv = fmaxf(c[r] + bias1[t], 0.0f);
                tile[(q * 4 + r) * 72 + t * 16 + m] = f32_to_bf16_rn(vv);
            }
        }

        // Layer-2 A-frags from LDS: A[m][k = s*32 + q*8 + j], 16B-aligned reads
        bf16x8 a2f[2];
        #pragma unroll
        for (int s = 0; s < 2; ++s)
            a2f[s] = *(const bf16x8*)&tile[m * 72 + s * 32 + q * 8];

        // Layer 2 + bias, store C-layout to global (4x 64B segments per store)
        #pragma unroll
        for (int t = 0; t < 4; ++t) {
            f32x4 c = {0.f, 0.f, 0.f, 0.f};
            c = __builtin_amdgcn_mfma_f32_16x16x32_bf16(a2f[0], wb2[t][0], c, 0, 0, 0);
            c = __builtin_amdgcn_mfma_f32_16x16x32_bf16(a2f[1], wb2[t][1], c, 0, 0, 0);
            #pragma unroll
            for (int r = 0; r < 4; ++r)
                h[(rowbase + q * 4 + r) * D + t * 16 + m] = c[r] + bias2[t];
        }
    }
}

extern "C" void kernel_launch(void* const* d_in, const int* in_sizes, int n_in,
                              void* d_out, int out_size, void* d_ws, size_t ws_size,
                              hipStream_t stream) {
    const float* x   = (const float*)d_in[0];
    const int*   ei  = (const int*)d_in[1];
    const float* W1  = (const float*)d_in[2];
    const float* b1  = (const float*)d_in[3];
    const float* W2  = (const float*)d_in[4];
    const float* b2  = (const float*)d_in[5];
    const float* eps = (const float*)d_in[6];
    float*       out = (float*)d_out;

    int* cursor = (int*)d_ws;
    int* bins   = cursor + NBK;
    u16* xb     = (u16*)(bins + NBK * CAP);

    hipMemsetAsync(cursor, 0, NBK * sizeof(int), stream);
    bin_cvt_kernel<<<NCH + CVTB, 256, 0, stream>>>(x, xb, ei, cursor, bins);
    agg_kernel<<<NBK, 1024, 0, stream>>>(x, xb, eps, cursor, bins, out);
    mlp_mfma_kernel<<<1024, 256, 0, stream>>>(out, W1, b1, W2, b2);
}

// Round 2
// 164.007 us; speedup vs baseline: 1.1045x; 1.1045x over previous
//
#include <hip/hip_runtime.h>

#define NN 100000      // nodes
#define NE 1600000     // edges
#define D  64          // feature dim
#define NBK 512        // dst buckets
#define NPB 196        // nodes per bucket; 512*196 = 100352 >= NN
#define RPL 8          // cursor/bins replicas (cuts per-address atomic contention)
#define CAPR 512       // slots per (bucket,replica); mean 392, sd 20 -> max ~473
#define CHUNK 2048     // edges per bin block (256 thr)
#define NCH ((NE + CHUNK - 1) / CHUNK)        // 782 bin blocks
#define CVTB ((NN * D / 4 + 255) / 256)       // 6250 cvt blocks

// ---- workspace: cursor[RPL*NBK] ints | bins[NBK*RPL*CAPR] ints | xb[NN*D] u16

typedef unsigned short u16;
typedef __attribute__((ext_vector_type(8))) short bf16x8;   // 4 VGPRs
typedef __attribute__((ext_vector_type(4))) float f32x4;

__device__ __forceinline__ u16 f32_to_bf16_rn(float f) {
    unsigned u = __float_as_uint(f);
    return (u16)((u + 0x7FFF + ((u >> 16) & 1)) >> 16);   // round-nearest-even
}
__device__ __forceinline__ float bflo(unsigned w) {       // bf16 in low half
    return __uint_as_float(w << 16);
}
__device__ __forceinline__ float bfhi(unsigned w) {       // bf16 in high half
    return __uint_as_float(w & 0xFFFF0000u);
}

// Fused binning + fp32->bf16 convert. R1 post-mortem: bin time was invariant
// to 4x blocks / 8x occupancy (VALU 3%, HBM 17%) -> serialized on the global
// cursor atomics (782 contended atomics PER cursor address). Fix: 8 cursor
// replicas selected by blockIdx%8 -> 98 atomics/address, replicas on
// different cache lines. bins memory unchanged (8 sub-regions of 512).
__global__ __launch_bounds__(256) void bin_cvt_kernel(const float* __restrict__ x,
                                                      u16* __restrict__ xb,
                                                      const int* __restrict__ ei,
                                                      int* __restrict__ cursor,
                                                      int* __restrict__ bins) {
    __shared__ int lc[NBK];
    __shared__ int lbase[NBK];
    const int t = threadIdx.x;

    if (blockIdx.x >= NCH) {
        // ---- cvt part: x (fp32) -> xb (bf16), float4 -> ushort4 ----
        int i = ((blockIdx.x - NCH) * 256 + t) * 4;       // NN*D % 4 == 0
        if (i < NN * D) {
            float4 v = *(const float4*)(x + i);
            ushort4 o;
            o.x = f32_to_bf16_rn(v.x);
            o.y = f32_to_bf16_rn(v.y);
            o.z = f32_to_bf16_rn(v.z);
            o.w = f32_to_bf16_rn(v.w);
            *(ushort4*)(xb + i) = o;
        }
        return;
    }

    // ---- bin part ----
    const int base = blockIdx.x * CHUNK;
    const int rep  = blockIdx.x & (RPL - 1);    // replica id

    for (int i = t; i < NBK; i += 256) lc[i] = 0;
    __syncthreads();
    #pragma unroll 4
    for (int j = 0; j < CHUNK / 256; ++j) {
        int e = base + t + j * 256;
        if (e < NE) atomicAdd(&lc[(unsigned)ei[NE + e] / NPB], 1);
    }
    __syncthreads();
    for (int i = t; i < NBK; i += 256) {
        int c = lc[i];
        lbase[i] = c ? atomicAdd(&cursor[rep * NBK + i], c) : 0;
        lc[i] = 0;                 // reuse as local offset counter
    }
    __syncthreads();
    #pragma unroll 4
    for (int j = 0; j < CHUNK / 256; ++j) {
        int e = base + t + j * 256;
        if (e < NE) {
            int src = ei[e];
            int dst = ei[NE + e];
            int b   = (unsigned)dst / NPB;
            int loc = dst - b * NPB;                  // < 196
            int o   = atomicAdd(&lc[b], 1);
            int pos = lbase[b] + o;
            if (pos < CAPR)                           // safety clamp
                bins[(b * RPL + rep) * CAPR + pos] = (loc << 17) | src;
        }
    }
}

// One 1024-thread block per bucket: LDS counting-sort of the 8 replica
// sub-lists by local node id, then register gather. R1 restructure: lanes
// split as (edge-slot g=lane>>4, feature-quad c=lane&15) -> one dwordx2 load
// covers 4 edges/instr (was 1 ushort load per edge); cross-group shfl_xor
// reduce per node. Writes h to d_out.
__global__ __launch_bounds__(1024) void agg_kernel(const float* __restrict__ x,
                                                   const u16* __restrict__ xb,
                                                   const float* __restrict__ eps,
                                                   const int* __restrict__ cursor,
                                                   const int* __restrict__ bins,
                                                   float* __restrict__ out) {
    __shared__ int sorted[RPL * CAPR];   // 16 KB
    __shared__ int tmp[256];
    __shared__ int off[256];       // off[r] = start of node r; off[196] == n
    __shared__ int cur[256];
    const int b    = blockIdx.x;
    const int t    = threadIdx.x;
    const int lane = t & 63;
    const int w    = t >> 6;       // 16 waves
    const float e1 = 1.0f + *eps;

    // ---- counting sort by local node id (over 8 replica sub-lists) ----
    if (t < 256) tmp[t] = 0;
    __syncthreads();
    int nrep[RPL];
    #pragma unroll
    for (int r = 0; r < RPL; ++r) nrep[r] = min(cursor[r * NBK + b], CAPR);
    #pragma unroll
    for (int r = 0; r < RPL; ++r) {
        const int rb = (b * RPL + r) * CAPR;
        for (int i = t; i < nrep[r]; i += 1024)
            atomicAdd(&tmp[bins[rb + i] >> 17], 1);
    }
    __syncthreads();
    int v = (t < 256) ? tmp[t] : 0;
    for (int o = 1; o < 256; o <<= 1) {            // inclusive scan
        int u = (t < 256 && t >= o) ? tmp[t - o] : 0;
        __syncthreads();
        if (t < 256) tmp[t] += u;
        __syncthreads();
    }
    if (t < 256) { off[t] = tmp[t] - v; cur[t] = tmp[t] - v; }
    __syncthreads();
    #pragma unroll
    for (int r = 0; r < RPL; ++r) {
        const int rb = (b * RPL + r) * CAPR;
        for (int i = t; i < nrep[r]; i += 1024) {
            int pk  = bins[rb + i];
            int pos = atomicAdd(&cur[pk >> 17], 1);
            sorted[pos] = pk & 0x1FFFF;
        }
    }
    __syncthreads();

    // ---- per-node register gather: 4 edges per load instruction ----
    const int g = lane >> 4;       // edge slot within group of 4
    const int c = lane & 15;       // feature quad: feats 4c..4c+3
    #pragma unroll
    for (int j = 0; j < 13; ++j) {
        int r = w + 16 * j;                        // 16 waves x 13 >= 196
        if (r < NPB) {
            int node = b * NPB + r;
            if (node < NN) {
                float4 a;
                if (g == 0) {                      // self term, added once
                    float4 xv = *(const float4*)(x + node * D + 4 * c);
                    a.x = e1 * xv.x; a.y = e1 * xv.y;
                    a.z = e1 * xv.z; a.w = e1 * xv.w;
                } else {
                    a.x = a.y = a.z = a.w = 0.f;
                }
                int p  = off[r];
                int pe = off[r + 1];               // counts[196..255]=0 -> valid
                for (; p + 8 <= pe; p += 8) {      // 2 loads in flight
                    int e0 = sorted[p + g];
                    int e1i = sorted[p + 4 + g];
                    uint2 v0 = *(const uint2*)(xb + e0 * D + 4 * c);
                    uint2 v1 = *(const uint2*)(xb + e1i * D + 4 * c);
                    a.x += bflo(v0.x) + bflo(v1.x);
                    a.y += bfhi(v0.x) + bfhi(v1.x);
                    a.z += bflo(v0.y) + bflo(v1.y);
                    a.w += bfhi(v0.y) + bfhi(v1.y);
                }
                for (; p + 4 <= pe; p += 4) {
                    int e0 = sorted[p + g];
                    uint2 v0 = *(const uint2*)(xb + e0 * D + 4 * c);
                    a.x += bflo(v0.x);
                    a.y += bfhi(v0.x);
                    a.z += bflo(v0.y);
                    a.w += bfhi(v0.y);
                }
                if (p < pe) {                      // 1..3 tail edges, masked
                    bool ok = (p + g) < pe;
                    int e0 = sorted[ok ? p + g : p];
                    uint2 v0 = *(const uint2*)(xb + e0 * D + 4 * c);
                    a.x += ok ? bflo(v0.x) : 0.f;
                    a.y += ok ? bfhi(v0.x) : 0.f;
                    a.z += ok ? bflo(v0.y) : 0.f;
                    a.w += ok ? bfhi(v0.y) : 0.f;
                }
                // cross-group reduce (wave-uniform control flow here)
                a.x += __shfl_xor(a.x, 16); a.x += __shfl_xor(a.x, 32);
                a.y += __shfl_xor(a.y, 16); a.y += __shfl_xor(a.y, 32);
                a.z += __shfl_xor(a.z, 16); a.z += __shfl_xor(a.z, 32);
                a.w += __shfl_xor(a.w, 16); a.w += __shfl_xor(a.w, 32);
                if (g == 0)
                    *(float4*)(out + node * D + 4 * c) = a;
            }
        }
    }
}

// MFMA MLP: one wave per 16-node tile. out = relu(h@W1+b1)@W2+b2 with bf16
// 16x16x32 MFMA (fp32 accum). Layer-1 C-layout (col=lane&15,row=quad*4+reg
// [m89]) re-enters layer 2 as A-layout (A[m=lane&15][k=quad*8+j] [m120]) via
// wave-private LDS tile (no barriers). In-place on d_out. R1: grid 1563 so
// each wave owns exactly one tile (no 1-vs-2 tail imbalance).
__global__ __launch_bounds__(256, 2) void mlp_mfma_kernel(
        float* __restrict__ h,
        const float* __restrict__ W1, const float* __restrict__ b1,
        const float* __restrict__ W2, const float* __restrict__ b2) {
    __shared__ u16 lds[4][16 * 72];   // per-wave tile, row stride 72 u16 (16B-aligned)
    const int lane = threadIdx.x & 63;
    const int wv   = threadIdx.x >> 6;
    const int m    = lane & 15;       // row-in-tile / col-in-output
    const int q    = lane >> 4;       // quad
    u16* tile = &lds[wv][0];

    // Weight B-frags: B[k = s*32 + q*8 + j][n = t*16 + m]; 16 frags = 64 VGPRs.
    bf16x8 wb1[4][2], wb2[4][2];
    #pragma unroll
    for (int t = 0; t < 4; ++t)
        #pragma unroll
        for (int s = 0; s < 2; ++s) {
            bf16x8 f1, f2;
            #pragma unroll
            for (int j = 0; j < 8; ++j) {
                int k = s * 32 + q * 8 + j;
                int nn = t * 16 + m;
                f1[j] = (short)f32_to_bf16_rn(W1[k * D + nn]);
                f2[j] = (short)f32_to_bf16_rn(W2[k * D + nn]);
            }
            wb1[t][s] = f1;
            wb2[t][s] = f2;
        }
    float bias1[4], bias2[4];
    #pragma unroll
    for (int t = 0; t < 4; ++t) {
        bias1[t] = b1[t * 16 + m];
        bias2[t] = b2[t * 16 + m];
    }

    const int wave = blockIdx.x * 4 + wv;
    const int nw   = gridDim.x * 4;
    for (int ti = wave; ti < NN / 16; ti += nw) {
        const int rowbase = ti * 16;

        // Layer-1 A-frags from fp32 h: A[m][k = s*32 + q*8 + j]
        bf16x8 a1f[2];
        #pragma unroll
        for (int s = 0; s < 2; ++s) {
            const float* p = h + (rowbase + m) * D + s * 32 + q * 8;
            float4 v0 = *(const float4*)p;
            float4 v1 = *(const float4*)(p + 4);
            bf16x8 f;
            f[0] = (short)f32_to_bf16_rn(v0.x);
            f[1] = (short)f32_to_bf16_rn(v0.y);
            f[2] = (short)f32_to_bf16_rn(v0.z);
            f[3] = (short)f32_to_bf16_rn(v0.w);
            f[4] = (short)f32_to_bf16_rn(v1.x);
            f[5] = (short)f32_to_bf16_rn(v1.y);
            f[6] = (short)f32_to_bf16_rn(v1.z);
            f[7] = (short)f32_to_bf16_rn(v1.w);
            a1f[s] = f;
        }

        // Layer 1: 4 n-tiles x 2 k-steps
        #pragma unroll
        for (int t = 0; t < 4; ++t) {
            f32x4 cc = {0.f, 0.f, 0.f, 0.f};
            cc = __builtin_amdgcn_mfma_f32_16x16x32_bf16(a1f[0], wb1[t][0], cc, 0, 0, 0);
            cc = __builtin_amdgcn_mfma_f32_16x16x32_bf16(a1f[1], wb1[t][1], cc, 0, 0, 0);
            // bias + relu, store C-layout -> LDS bf16 tile
            #pragma unroll
            for (int r = 0; r < 4; ++r) {
                float vv = fmaxf(cc[r] + bias1[t], 0.0f);
                tile[(q * 4 + r) * 72 + t * 16 + m] = f32_to_bf16_rn(vv);
            }
        }

        // Layer-2 A-frags from LDS: A[m][k = s*32 + q*8 + j], 16B-aligned reads
        bf16x8 a2f[2];
        #pragma unroll
        for (int s = 0; s < 2; ++s)
            a2f[s] = *(const bf16x8*)&tile[m * 72 + s * 32 + q * 8];

        // Layer 2 + bias, store C-layout to global (4x 64B segments per store)
        #pragma unroll
        for (int t = 0; t < 4; ++t) {
            f32x4 cc = {0.f, 0.f, 0.f, 0.f};
            cc = __builtin_amdgcn_mfma_f32_16x16x32_bf16(a2f[0], wb2[t][0], cc, 0, 0, 0);
            cc = __builtin_amdgcn_mfma_f32_16x16x32_bf16(a2f[1], wb2[t][1], cc, 0, 0, 0);
            #pragma unroll
            for (int r = 0; r < 4; ++r)
                h[(rowbase + q * 4 + r) * D + t * 16 + m] = cc[r] + bias2[t];
        }
    }
}

extern "C" void kernel_launch(void* const* d_in, const int* in_sizes, int n_in,
                              void* d_out, int out_size, void* d_ws, size_t ws_size,
                              hipStream_t stream) {
    const float* x   = (const float*)d_in[0];
    const int*   ei  = (const int*)d_in[1];
    const float* W1  = (const float*)d_in[2];
    const float* b1  = (const float*)d_in[3];
    const float* W2  = (const float*)d_in[4];
    const float* b2  = (const float*)d_in[5];
    const float* eps = (const float*)d_in[6];
    float*       out = (float*)d_out;

    int* cursor = (int*)d_ws;
    int* bins   = cursor + RPL * NBK;
    u16* xb     = (u16*)(bins + NBK * RPL * CAPR);

    hipMemsetAsync(cursor, 0, RPL * NBK * sizeof(int), stream);
    bin_cvt_kernel<<<NCH + CVTB, 256, 0, stream>>>(x, xb, ei, cursor, bins);
    agg_kernel<<<NBK, 1024, 0, stream>>>(x, xb, eps, cursor, bins, out);
    mlp_mfma_kernel<<<1563, 256, 0, stream>>>(out, W1, b1, W2, b2);
}

// Round 3
// 158.981 us; speedup vs baseline: 1.1394x; 1.0316x over previous
//
#include <hip/hip_runtime.h>

#define NN 100000      // nodes
#define NE 1600000     // edges
#define D  64          // feature dim
#define NBK 512        // dst buckets
#define NPB 196        // nodes per bucket; 512*196 = 100352 >= NN
#define RPL 8          // cursor/bins replicas (cuts per-address atomic contention)
#define CAPR 512       // slots per (bucket,replica); mean 392, sd 20 -> max ~473
#define CHUNK 2048     // edges per bin block (256 thr)
#define NCH ((NE + CHUNK - 1) / CHUNK)        // 782 bin blocks
#define CVTB ((NN * D / 4 + 255) / 256)       // 6250 cvt blocks

// ---- workspace: cursor[RPL*NBK] ints | bins[NBK*RPL*CAPR] ints | xb[NN*D] u16

typedef unsigned short u16;
typedef __attribute__((ext_vector_type(8))) short bf16x8;   // 4 VGPRs
typedef __attribute__((ext_vector_type(4))) float f32x4;

__device__ __forceinline__ u16 f32_to_bf16_rn(float f) {
    unsigned u = __float_as_uint(f);
    return (u16)((u + 0x7FFF + ((u >> 16) & 1)) >> 16);   // round-nearest-even
}
__device__ __forceinline__ float bflo(unsigned w) {       // bf16 in low half
    return __uint_as_float(w << 16);
}
__device__ __forceinline__ float bfhi(unsigned w) {       // bf16 in high half
    return __uint_as_float(w & 0xFFFF0000u);
}

// Fused binning + fp32->bf16 convert. R1 post-mortem: bin time was invariant
// to 4x blocks / 8x occupancy (VALU 3%, HBM 17%) -> serialized on the global
// cursor atomics (782 contended atomics PER cursor address). Fix: 8 cursor
// replicas selected by blockIdx%8 -> 98 atomics/address, replicas on
// different cache lines. bins memory unchanged (8 sub-regions of 512).
__global__ __launch_bounds__(256) void bin_cvt_kernel(const float* __restrict__ x,
                                                      u16* __restrict__ xb,
                                                      const int* __restrict__ ei,
                                                      int* __restrict__ cursor,
                                                      int* __restrict__ bins) {
    __shared__ int lc[NBK];
    __shared__ int lbase[NBK];
    const int t = threadIdx.x;

    if (blockIdx.x >= NCH) {
        // ---- cvt part: x (fp32) -> xb (bf16), float4 -> ushort4 ----
        int i = ((blockIdx.x - NCH) * 256 + t) * 4;       // NN*D % 4 == 0
        if (i < NN * D) {
            float4 v = *(const float4*)(x + i);
            ushort4 o;
            o.x = f32_to_bf16_rn(v.x);
            o.y = f32_to_bf16_rn(v.y);
            o.z = f32_to_bf16_rn(v.z);
            o.w = f32_to_bf16_rn(v.w);
            *(ushort4*)(xb + i) = o;
        }
        return;
    }

    // ---- bin part ----
    const int base = blockIdx.x * CHUNK;
    const int rep  = blockIdx.x & (RPL - 1);    // replica id

    for (int i = t; i < NBK; i += 256) lc[i] = 0;
    __syncthreads();
    #pragma unroll 4
    for (int j = 0; j < CHUNK / 256; ++j) {
        int e = base + t + j * 256;
        if (e < NE) atomicAdd(&lc[(unsigned)ei[NE + e] / NPB], 1);
    }
    __syncthreads();
    for (int i = t; i < NBK; i += 256) {
        int c = lc[i];
        lbase[i] = c ? atomicAdd(&cursor[rep * NBK + i], c) : 0;
        lc[i] = 0;                 // reuse as local offset counter
    }
    __syncthreads();
    #pragma unroll 4
    for (int j = 0; j < CHUNK / 256; ++j) {
        int e = base + t + j * 256;
        if (e < NE) {
            int src = ei[e];
            int dst = ei[NE + e];
            int b   = (unsigned)dst / NPB;
            int loc = dst - b * NPB;                  // < 196
            int o   = atomicAdd(&lc[b], 1);
            int pos = lbase[b] + o;
            if (pos < CAPR)                           // safety clamp
                bins[(b * RPL + rep) * CAPR + pos] = (loc << 17) | src;
        }
    }
}

// One 1024-thread block per bucket: LDS counting-sort of the 8 replica
// sub-lists by local node id, then register gather. Lanes split as (edge-slot
// g=lane>>4, feature-quad c=lane&15) -> one dwordx2 load covers 4 edges/instr;
// cross-group shfl_xor reduce per node. Writes h to d_out.
__global__ __launch_bounds__(1024) void agg_kernel(const float* __restrict__ x,
                                                   const u16* __restrict__ xb,
                                                   const float* __restrict__ eps,
                                                   const int* __restrict__ cursor,
                                                   const int* __restrict__ bins,
                                                   float* __restrict__ out) {
    __shared__ int sorted[RPL * CAPR];   // 16 KB
    __shared__ int tmp[256];
    __shared__ int off[256];       // off[r] = start of node r; off[196] == n
    __shared__ int cur[256];
    const int b    = blockIdx.x;
    const int t    = threadIdx.x;
    const int lane = t & 63;
    const int w    = t >> 6;       // 16 waves
    const float e1 = 1.0f + *eps;

    // ---- counting sort by local node id (over 8 replica sub-lists) ----
    if (t < 256) tmp[t] = 0;
    __syncthreads();
    int nrep[RPL];
    #pragma unroll
    for (int r = 0; r < RPL; ++r) nrep[r] = min(cursor[r * NBK + b], CAPR);
    #pragma unroll
    for (int r = 0; r < RPL; ++r) {
        const int rb = (b * RPL + r) * CAPR;
        for (int i = t; i < nrep[r]; i += 1024)
            atomicAdd(&tmp[bins[rb + i] >> 17], 1);
    }
    __syncthreads();
    int v = (t < 256) ? tmp[t] : 0;
    for (int o = 1; o < 256; o <<= 1) {            // inclusive scan
        int u = (t < 256 && t >= o) ? tmp[t - o] : 0;
        __syncthreads();
        if (t < 256) tmp[t] += u;
        __syncthreads();
    }
    if (t < 256) { off[t] = tmp[t] - v; cur[t] = tmp[t] - v; }
    __syncthreads();
    #pragma unroll
    for (int r = 0; r < RPL; ++r) {
        const int rb = (b * RPL + r) * CAPR;
        for (int i = t; i < nrep[r]; i += 1024) {
            int pk  = bins[rb + i];
            int pos = atomicAdd(&cur[pk >> 17], 1);
            sorted[pos] = pk & 0x1FFFF;
        }
    }
    __syncthreads();

    // ---- per-node register gather: 4 edges per load instruction ----
    const int g = lane >> 4;       // edge slot within group of 4
    const int c = lane & 15;       // feature quad: feats 4c..4c+3
    #pragma unroll
    for (int j = 0; j < 13; ++j) {
        int r = w + 16 * j;                        // 16 waves x 13 >= 196
        if (r < NPB) {
            int node = b * NPB + r;
            if (node < NN) {
                float4 a;
                if (g == 0) {                      // self term, added once
                    float4 xv = *(const float4*)(x + node * D + 4 * c);
                    a.x = e1 * xv.x; a.y = e1 * xv.y;
                    a.z = e1 * xv.z; a.w = e1 * xv.w;
                } else {
                    a.x = a.y = a.z = a.w = 0.f;
                }
                int p  = off[r];
                int pe = off[r + 1];               // counts[196..255]=0 -> valid
                for (; p + 8 <= pe; p += 8) {      // 2 loads in flight
                    int e0 = sorted[p + g];
                    int e1i = sorted[p + 4 + g];
                    uint2 v0 = *(const uint2*)(xb + e0 * D + 4 * c);
                    uint2 v1 = *(const uint2*)(xb + e1i * D + 4 * c);
                    a.x += bflo(v0.x) + bflo(v1.x);
                    a.y += bfhi(v0.x) + bfhi(v1.x);
                    a.z += bflo(v0.y) + bflo(v1.y);
                    a.w += bfhi(v0.y) + bfhi(v1.y);
                }
                for (; p + 4 <= pe; p += 4) {
                    int e0 = sorted[p + g];
                    uint2 v0 = *(const uint2*)(xb + e0 * D + 4 * c);
                    a.x += bflo(v0.x);
                    a.y += bfhi(v0.x);
                    a.z += bflo(v0.y);
                    a.w += bfhi(v0.y);
                }
                if (p < pe) {                      // 1..3 tail edges, masked
                    bool ok = (p + g) < pe;
                    int e0 = sorted[ok ? p + g : p];
                    uint2 v0 = *(const uint2*)(xb + e0 * D + 4 * c);
                    a.x += ok ? bflo(v0.x) : 0.f;
                    a.y += ok ? bfhi(v0.x) : 0.f;
                    a.z += ok ? bflo(v0.y) : 0.f;
                    a.w += ok ? bfhi(v0.y) : 0.f;
                }
                // cross-group reduce (wave-uniform control flow here)
                a.x += __shfl_xor(a.x, 16); a.x += __shfl_xor(a.x, 32);
                a.y += __shfl_xor(a.y, 16); a.y += __shfl_xor(a.y, 32);
                a.z += __shfl_xor(a.z, 16); a.z += __shfl_xor(a.z, 32);
                a.w += __shfl_xor(a.w, 16); a.w += __shfl_xor(a.w, 32);
                if (g == 0)
                    *(float4*)(out + node * D + 4 * c) = a;
            }
        }
    }
}

// MFMA MLP: out = relu(h@W1+b1)@W2+b2, bf16 16x16x32 MFMA (fp32 accum).
// R2 post-mortem: grid 1563 meant ~1 tile/wave, so the per-wave weight
// prologue (128 strided scalar fp32 loads + cvt) dominated. R3: stage W1/W2
// ONCE per block into LDS transposed-bf16 Wt[n][k] (coalesced global reads;
// frag k-runs contiguous -> ds_read_b128), each wave copies frags to VGPRs
// once, then grid-strides over ~6 tiles. Layer-1 C-layout (col=lane&15,
// row=quad*4+reg [m89]) re-enters layer 2 as A-layout via wave-private LDS
// tile (no barriers). In-place on d_out.
#define WSTR 72   // u16 row stride for LDS weight/h tiles (144 B, 16B-aligned)
__global__ __launch_bounds__(256, 2) void mlp_mfma_kernel(
        float* __restrict__ h,
        const float* __restrict__ W1, const float* __restrict__ b1,
        const float* __restrict__ W2, const float* __restrict__ b2) {
    __shared__ u16 wt1[D * WSTR];     // 9 KB, Wt1[n][k] = W1[k][n] bf16
    __shared__ u16 wt2[D * WSTR];     // 9 KB
    __shared__ u16 lds[4][16 * WSTR]; // per-wave h tile, 9 KB
    const int lane = threadIdx.x & 63;
    const int wv   = threadIdx.x >> 6;
    const int m    = lane & 15;       // row-in-tile / col-in-output
    const int q    = lane >> 4;       // quad
    u16* tile = &lds[wv][0];

    // ---- block prologue: coalesced W load -> transposed bf16 LDS ----
    for (int i = threadIdx.x; i < D * D; i += 256) {
        int k = i >> 6, n = i & 63;            // W[k][n], i contiguous over n
        wt1[n * WSTR + k] = f32_to_bf16_rn(W1[i]);
        wt2[n * WSTR + k] = f32_to_bf16_rn(W2[i]);
    }
    __syncthreads();

    // ---- per-wave: copy weight frags LDS -> VGPRs (once) ----
    // frag f[j] = W[k = s*32 + q*8 + j][n = t*16 + m] = wt[(t*16+m)*WSTR + s*32+q*8+j]
    bf16x8 wb1[4][2], wb2[4][2];
    #pragma unroll
    for (int t = 0; t < 4; ++t)
        #pragma unroll
        for (int s = 0; s < 2; ++s) {
            const int o = (t * 16 + m) * WSTR + s * 32 + q * 8;
            wb1[t][s] = *(const bf16x8*)&wt1[o];
            wb2[t][s] = *(const bf16x8*)&wt2[o];
        }
    float bias1[4], bias2[4];
    #pragma unroll
    for (int t = 0; t < 4; ++t) {
        bias1[t] = b1[t * 16 + m];
        bias2[t] = b2[t * 16 + m];
    }

    const int wave = blockIdx.x * 4 + wv;
    const int nw   = gridDim.x * 4;
    for (int ti = wave; ti < NN / 16; ti += nw) {
        const int rowbase = ti * 16;

        // Layer-1 A-frags from fp32 h: A[m][k = s*32 + q*8 + j]
        bf16x8 a1f[2];
        #pragma unroll
        for (int s = 0; s < 2; ++s) {
            const float* p = h + (rowbase + m) * D + s * 32 + q * 8;
            float4 v0 = *(const float4*)p;
            float4 v1 = *(const float4*)(p + 4);
            bf16x8 f;
            f[0] = (short)f32_to_bf16_rn(v0.x);
            f[1] = (short)f32_to_bf16_rn(v0.y);
            f[2] = (short)f32_to_bf16_rn(v0.z);
            f[3] = (short)f32_to_bf16_rn(v0.w);
            f[4] = (short)f32_to_bf16_rn(v1.x);
            f[5] = (short)f32_to_bf16_rn(v1.y);
            f[6] = (short)f32_to_bf16_rn(v1.z);
            f[7] = (short)f32_to_bf16_rn(v1.w);
            a1f[s] = f;
        }

        // Layer 1: 4 n-tiles x 2 k-steps
        #pragma unroll
        for (int t = 0; t < 4; ++t) {
            f32x4 cc = {0.f, 0.f, 0.f, 0.f};
            cc = __builtin_amdgcn_mfma_f32_16x16x32_bf16(a1f[0], wb1[t][0], cc, 0, 0, 0);
            cc = __builtin_amdgcn_mfma_f32_16x16x32_bf16(a1f[1], wb1[t][1], cc, 0, 0, 0);
            // bias + relu, store C-layout -> LDS bf16 tile
            #pragma unroll
            for (int r = 0; r < 4; ++r) {
                float vv = fmaxf(cc[r] + bias1[t], 0.0f);
                tile[(q * 4 + r) * WSTR + t * 16 + m] = f32_to_bf16_rn(vv);
            }
        }

        // Layer-2 A-frags from LDS: A[m][k = s*32 + q*8 + j], 16B-aligned reads
        bf16x8 a2f[2];
        #pragma unroll
        for (int s = 0; s < 2; ++s)
            a2f[s] = *(const bf16x8*)&tile[m * WSTR + s * 32 + q * 8];

        // Layer 2 + bias, store C-layout to global (4x 64B segments per store)
        #pragma unroll
        for (int t = 0; t < 4; ++t) {
            f32x4 cc = {0.f, 0.f, 0.f, 0.f};
            cc = __builtin_amdgcn_mfma_f32_16x16x32_bf16(a2f[0], wb2[t][0], cc, 0, 0, 0);
            cc = __builtin_amdgcn_mfma_f32_16x16x32_bf16(a2f[1], wb2[t][1], cc, 0, 0, 0);
            #pragma unroll
            for (int r = 0; r < 4; ++r)
                h[(rowbase + q * 4 + r) * D + t * 16 + m] = cc[r] + bias2[t];
        }
    }
}

extern "C" void kernel_launch(void* const* d_in, const int* in_sizes, int n_in,
                              void* d_out, int out_size, void* d_ws, size_t ws_size,
                              hipStream_t stream) {
    const float* x   = (const float*)d_in[0];
    const int*   ei  = (const int*)d_in[1];
    const float* W1  = (const float*)d_in[2];
    const float* b1  = (const float*)d_in[3];
    const float* W2  = (const float*)d_in[4];
    const float* b2  = (const float*)d_in[5];
    const float* eps = (const float*)d_in[6];
    float*       out = (float*)d_out;

    int* cursor = (int*)d_ws;
    int* bins   = cursor + RPL * NBK;
    u16* xb     = (u16*)(bins + NBK * RPL * CAPR);

    hipMemsetAsync(cursor, 0, RPL * NBK * sizeof(int), stream);
    bin_cvt_kernel<<<NCH + CVTB, 256, 0, stream>>>(x, xb, ei, cursor, bins);
    agg_kernel<<<NBK, 1024, 0, stream>>>(x, xb, eps, cursor, bins, out);
    mlp_mfma_kernel<<<1024, 256, 0, stream>>>(out, W1, b1, W2, b2);
}